// Round 5
// baseline (113.376 us; speedup 1.0000x reference)
//
#include <hip/hip_runtime.h>
#include <math.h>

#define KCOMP 8
#define DDIM  16

typedef __attribute__((ext_vector_type(8))) short bf16x8;
typedef __attribute__((ext_vector_type(4))) float f32x4;

// fp32 -> bf16 bits, round-to-nearest-even (inputs are finite)
static __device__ __forceinline__ short f2bf(float f) {
    unsigned u = __float_as_uint(f);
    unsigned r = (u + 0x7FFFu + ((u >> 16) & 1u)) >> 16;
    return (short)r;
}

// Single fused kernel:
//  Phase 1 (threads 0..127): per-component Cholesky of sigma + L^-1 via
//    width-16 shuffles, results to LDS (sLinv, sB=Linv.mu, sC=log pi - logdet
//    - D/2 log 2pi). ~0.5us per block, sigma is L2-broadcast.
//  Phase 2 (all 4 waves): MFMA scoring. Y_k = Linv_k z - b_k as one
//    mfma_f32_16x16x32_bf16 per (component, 16-sample tile) with augmented
//    input z~=[z,1] (K 17 padded to 32), A = [Linv_k | -b_k].
//    Verified layouts: A[m=lane&15][k=quad*8+j], B[k=quad*8+j][n=lane&15],
//    D: col=lane&15, row=quad*4+reg.
//  Epilogue: pk[tile][k] quad-reduced, then quad-select BEFORE the LSE so
//    each lane does exactly one 8-component log-sum-exp (8 exp + 1 log per
//    sample, vs 4x-redundant online LSE in round 4).
__global__ __launch_bounds__(256) void dagmm_kernel(
    const float* __restrict__ mu, const float* __restrict__ sigma,
    const float* __restrict__ pi, const float* __restrict__ z,
    float* __restrict__ out, int n)
{
    __shared__ float sLinv[KCOMP * DDIM * DDIM];
    __shared__ float sB[KCOMP * DDIM];
    __shared__ float sC[KCOMP];

    const int tid = threadIdx.x;

    // ---------- Phase 1: prep (threads 0..127 = 8 groups x 16 lanes) ------
    if (tid < 128) {
        const int g = tid >> 4;   // component
        const int r = tid & 15;   // row (cholesky) / column (inverse)

        float a[DDIM];
        const float4* srow = (const float4*)(sigma + g * DDIM * DDIM + r * DDIM);
        float4 v0 = srow[0], v1 = srow[1], v2 = srow[2], v3 = srow[3];
        a[0]=v0.x;  a[1]=v0.y;  a[2]=v0.z;  a[3]=v0.w;
        a[4]=v1.x;  a[5]=v1.y;  a[6]=v1.z;  a[7]=v1.w;
        a[8]=v2.x;  a[9]=v2.y;  a[10]=v2.z; a[11]=v2.w;
        a[12]=v3.x; a[13]=v3.y; a[14]=v3.z; a[15]=v3.w;

        // Cholesky: lane r computes row r of L via width-16 shuffles.
        float l[DDIM];
        #pragma unroll
        for (int j = 0; j < DDIM; ++j) {
            float s = a[j];
            #pragma unroll
            for (int m2 = 0; m2 < j; ++m2)
                s -= l[m2] * __shfl(l[m2], j, DDIM);
            float dj = sqrtf(__shfl(s, j, DDIM));
            float val;
            if (r == j)      val = dj;
            else if (r > j)  val = s / dj;
            else             val = 0.0f;
            l[j] = val;
        }

        // Invert L: lane r computes column r of Linv (forward substitution).
        float x[DDIM];
        #pragma unroll
        for (int i = 0; i < DDIM; ++i) {
            float t = (r == i) ? 1.0f : 0.0f;
            #pragma unroll
            for (int m2 = 0; m2 < i; ++m2)
                t -= __shfl(l[m2], i, DDIM) * x[m2];
            x[i] = t / __shfl(l[i], i, DDIM);
        }

        // Store Linv row-major: lane r holds column r -> element [i][r]
        #pragma unroll
        for (int i = 0; i < DDIM; ++i)
            sLinv[g * 256 + i * DDIM + r] = x[i];

        // b_r = sum_c Linv[r][c] * mu[c]   (same-wave LDS visibility)
        float b = 0.0f;
        #pragma unroll
        for (int c = 0; c < DDIM; ++c)
            b += sLinv[g * 256 + r * DDIM + c] * mu[g * DDIM + c];
        sB[g * DDIM + r] = b;

        // logdet = sum_r log(L_rr)
        float ld = logf(l[r]);
        #pragma unroll
        for (int off = 8; off >= 1; off >>= 1)
            ld += __shfl_xor(ld, off, DDIM);
        if (r == 0) {
            const float LOG2PI = 1.8378770664093454f;
            sC[g] = logf(pi[g]) - ld - 0.5f * DDIM * LOG2PI;
        }
    }
    __syncthreads();

    // ---------- Phase 2: MFMA scoring (all waves) -------------------------
    const int lane = tid & 63;
    const int m    = lane & 15;
    const int quad = lane >> 4;
    const int wave = (blockIdx.x * 256 + tid) >> 6;

    // A fragments for all 8 components: 32 VGPRs, reused for every sample.
    bf16x8 afrag[KCOMP];
    #pragma unroll
    for (int k = 0; k < KCOMP; ++k) {
        bf16x8 a = {0,0,0,0,0,0,0,0};
        if (quad < 2) {
            const float* Lrow = &sLinv[k * 256 + m * DDIM + quad * 8];
            #pragma unroll
            for (int j = 0; j < 8; ++j) a[j] = f2bf(Lrow[j]);
        } else if (quad == 2) {
            a[0] = f2bf(-sB[k * DDIM + m]);   // K-index 16: -b_k[i]
        }
        afrag[k] = a;
    }
    float ck[KCOMP];
    #pragma unroll
    for (int k = 0; k < KCOMP; ++k) ck[k] = sC[k];

    const f32x4 zero4 = {0.f, 0.f, 0.f, 0.f};
    const int base = wave * 256;          // 256 samples per wave

    #pragma unroll 1
    for (int it = 0; it < 4; ++it) {
        const int tb = base + it * 64;    // 64 samples = 4 tiles of 16
        float pk[4][KCOMP];

        #pragma unroll
        for (int t = 0; t < 4; ++t) {
            bf16x8 bfrag = {0,0,0,0,0,0,0,0};
            const int s = tb + t * 16 + m;
            if (quad < 2) {
                if (s < n) {
                    const float* zp = z + (size_t)s * DDIM + quad * 8;
                    #pragma unroll
                    for (int j = 0; j < 8; ++j) bfrag[j] = f2bf(zp[j]);
                }
            } else if (quad == 2) {
                bfrag[0] = (short)0x3F80;   // bf16(1.0) bias row
            }

            #pragma unroll
            for (int k = 0; k < KCOMP; ++k) {
                f32x4 d4 = __builtin_amdgcn_mfma_f32_16x16x32_bf16(
                               afrag[k], bfrag, zero4, 0, 0, 0);
                float p = d4[0]*d4[0] + d4[1]*d4[1] + d4[2]*d4[2] + d4[3]*d4[3];
                p += __shfl_xor(p, 16, 64);
                p += __shfl_xor(p, 32, 64);   // all lanes: maha for sample col m
                pk[t][k] = p;
            }
        }

        // Quad-select BEFORE the LSE: lane (quad,m) handles sample tb+quad*16+m.
        float lp[KCOMP];
        #pragma unroll
        for (int k = 0; k < KCOMP; ++k) {
            float p = pk[0][k];
            p = (quad == 1) ? pk[1][k] : p;
            p = (quad == 2) ? pk[2][k] : p;
            p = (quad == 3) ? pk[3][k] : p;
            lp[k] = fmaf(-0.5f, p, ck[k]);
        }
        float mx = lp[0];
        #pragma unroll
        for (int k = 1; k < KCOMP; ++k) mx = fmaxf(mx, lp[k]);
        float dens = 0.0f;
        #pragma unroll
        for (int k = 0; k < KCOMP; ++k) dens += __expf(lp[k] - mx);

        const int so = tb + quad * 16 + m;
        if (so < n) out[so] = -(mx + __logf(dens));
    }
}

extern "C" void kernel_launch(void* const* d_in, const int* in_sizes, int n_in,
                              void* d_out, int out_size, void* d_ws, size_t ws_size,
                              hipStream_t stream) {
    const float* mu    = (const float*)d_in[0];
    const float* sigma = (const float*)d_in[1];
    const float* z     = (const float*)d_in[2];
    const float* pi    = (const float*)d_in[3];
    float* out = (float*)d_out;
    (void)d_ws; (void)ws_size;

    const int n = in_sizes[2] / DDIM;       // number of samples (524288)

    // 256 threads = 4 waves/block, 256 samples/wave -> 1024 samples/block
    const int blocks = (n + 1023) / 1024;   // 512
    dagmm_kernel<<<blocks, 256, 0, stream>>>(mu, sigma, pi, z, out, n);
}

// Round 6
// 94.443 us; speedup vs baseline: 1.2005x; 1.2005x over previous
//
#include <hip/hip_runtime.h>
#include <math.h>

#define KCOMP 8
#define DDIM  16

typedef __attribute__((ext_vector_type(8))) short bf16x8;
typedef __attribute__((ext_vector_type(4))) float f32x4;

// fp32 -> bf16 bits, round-to-nearest-even (inputs are finite)
static __device__ __forceinline__ unsigned short f2bf(float f) {
    unsigned u = __float_as_uint(f);
    unsigned r = (u + 0x7FFFu + ((u >> 16) & 1u)) >> 16;
    return (unsigned short)r;
}

// ws layout:
//   bytes [0, 8192)      afrag table: entry e = k*64 + lane, 16 B each
//                        (8 bf16 = the lane's A-fragment for component k)
//   floats [2048, 2056)  ck[k] = log(pi_k) - logdet_k - D/2 log 2pi
//
// A-fragment semantics (mfma_f32_16x16x32_bf16, A[m=lane&15][kk=quad*8+j]):
//   quad 0/1 : Linv_k[m][quad*8 + j]
//   quad 2   : j==0 -> -b_k[m]  (kk=16, pairs with B's bias-1 row), else 0
//   quad 3   : 0
__global__ __launch_bounds__(128) void prep_kernel(
    const float* __restrict__ mu, const float* __restrict__ sigma,
    const float* __restrict__ pi, float* __restrict__ ws)
{
    __shared__ float sLinv[KCOMP * DDIM * DDIM];
    __shared__ float sB[KCOMP * DDIM];
    __shared__ float sC[KCOMP];

    const int tid = threadIdx.x;
    const int g = tid >> 4;   // component
    const int r = tid & 15;   // row (cholesky) / column (inverse)

    float a[DDIM];
    const float4* srow = (const float4*)(sigma + g * DDIM * DDIM + r * DDIM);
    float4 v0 = srow[0], v1 = srow[1], v2 = srow[2], v3 = srow[3];
    a[0]=v0.x;  a[1]=v0.y;  a[2]=v0.z;  a[3]=v0.w;
    a[4]=v1.x;  a[5]=v1.y;  a[6]=v1.z;  a[7]=v1.w;
    a[8]=v2.x;  a[9]=v2.y;  a[10]=v2.z; a[11]=v2.w;
    a[12]=v3.x; a[13]=v3.y; a[14]=v3.z; a[15]=v3.w;

    // Cholesky: lane r computes row r of L via width-16 shuffles.
    float l[DDIM];
    #pragma unroll
    for (int j = 0; j < DDIM; ++j) {
        float s = a[j];
        #pragma unroll
        for (int m2 = 0; m2 < j; ++m2)
            s -= l[m2] * __shfl(l[m2], j, DDIM);
        float dj = sqrtf(__shfl(s, j, DDIM));
        float val;
        if (r == j)      val = dj;
        else if (r > j)  val = s / dj;
        else             val = 0.0f;
        l[j] = val;
    }

    // Invert L: lane r computes column r of Linv (forward substitution).
    float x[DDIM];
    #pragma unroll
    for (int i = 0; i < DDIM; ++i) {
        float t = (r == i) ? 1.0f : 0.0f;
        #pragma unroll
        for (int m2 = 0; m2 < i; ++m2)
            t -= __shfl(l[m2], i, DDIM) * x[m2];
        x[i] = t / __shfl(l[i], i, DDIM);
    }

    // Store Linv row-major: lane r holds column r -> element [i][r]
    #pragma unroll
    for (int i = 0; i < DDIM; ++i)
        sLinv[g * 256 + i * DDIM + r] = x[i];

    // b_r = sum_c Linv[r][c] * mu[c]  (same-wave LDS visibility)
    float b = 0.0f;
    #pragma unroll
    for (int c = 0; c < DDIM; ++c)
        b += sLinv[g * 256 + r * DDIM + c] * mu[g * DDIM + c];
    sB[g * DDIM + r] = b;

    // logdet = sum_r log(L_rr)
    float ld = logf(l[r]);
    #pragma unroll
    for (int off = 8; off >= 1; off >>= 1)
        ld += __shfl_xor(ld, off, DDIM);
    if (r == 0) {
        const float LOG2PI = 1.8378770664093454f;
        sC[g] = logf(pi[g]) - ld - 0.5f * DDIM * LOG2PI;
    }
    __syncthreads();

    // Emit the bf16 afrag table: 512 entries, 4 per thread.
    #pragma unroll
    for (int i = 0; i < 4; ++i) {
        const int e    = tid + i * 128;
        const int k    = e >> 6;
        const int lane = e & 63;
        const int m    = lane & 15;
        const int quad = lane >> 4;
        float vals[8];
        #pragma unroll
        for (int j = 0; j < 8; ++j) vals[j] = 0.0f;
        if (quad < 2) {
            #pragma unroll
            for (int j = 0; j < 8; ++j)
                vals[j] = sLinv[k * 256 + m * DDIM + quad * 8 + j];
        } else if (quad == 2) {
            vals[0] = -sB[k * DDIM + m];
        }
        uint4 p;
        p.x = (unsigned)f2bf(vals[0]) | ((unsigned)f2bf(vals[1]) << 16);
        p.y = (unsigned)f2bf(vals[2]) | ((unsigned)f2bf(vals[3]) << 16);
        p.z = (unsigned)f2bf(vals[4]) | ((unsigned)f2bf(vals[5]) << 16);
        p.w = (unsigned)f2bf(vals[6]) | ((unsigned)f2bf(vals[7]) << 16);
        ((uint4*)ws)[e] = p;
    }
    if (tid < KCOMP) ws[2048 + tid] = sC[tid];
}

// Scoring: one wave = 64 samples = 4 tiles of 16. A fragments come straight
// from the prebuilt table (8 x dwordx4). B = z~^T per tile (z in quads 0/1,
// bf16(1.0) bias at kk=16 in quad 2). D: col=lane&15 (sample), row=quad*4+reg.
// maha broadcast via 2 shfl_xor; each lane keeps lp[k] only for ITS sample
// (quad==t select) -> one 8-way LSE per sample, no big arrays, no LDS.
__global__ __launch_bounds__(256, 4) void energy_kernel(
    const float* __restrict__ z, const float* __restrict__ ws,
    float* __restrict__ out, int n)
{
    const int tid  = threadIdx.x;
    const int lane = tid & 63;
    const int m    = lane & 15;
    const int quad = lane >> 4;
    const int base = ((blockIdx.x * 256 + tid) >> 6) * 64;

    // A fragments: 8 x 16B loads, L2-resident
    bf16x8 afrag[KCOMP];
    #pragma unroll
    for (int k = 0; k < KCOMP; ++k)
        afrag[k] = ((const bf16x8*)ws)[k * 64 + lane];

    // ck: uniform scalar loads
    float ck[KCOMP];
    #pragma unroll
    for (int k = 0; k < KCOMP; ++k) ck[k] = ws[2048 + k];

    // Prefetch all 4 z-tiles (2 x float4 per lane in quads 0/1)
    bf16x8 bfrag[4];
    #pragma unroll
    for (int t = 0; t < 4; ++t) {
        bf16x8 bf = {0,0,0,0,0,0,0,0};
        const int s = base + t * 16 + m;
        if (quad < 2) {
            if (s < n) {
                const float4* zp = (const float4*)(z + (size_t)s * DDIM + quad * 8);
                float4 w0 = zp[0], w1 = zp[1];
                bf[0]=(short)f2bf(w0.x); bf[1]=(short)f2bf(w0.y);
                bf[2]=(short)f2bf(w0.z); bf[3]=(short)f2bf(w0.w);
                bf[4]=(short)f2bf(w1.x); bf[5]=(short)f2bf(w1.y);
                bf[6]=(short)f2bf(w1.z); bf[7]=(short)f2bf(w1.w);
            }
        } else if (quad == 2) {
            bf[0] = (short)0x3F80;   // bf16(1.0) bias row (kk = 16)
        }
        bfrag[t] = bf;
    }

    const f32x4 zero4 = {0.f, 0.f, 0.f, 0.f};
    float lp[KCOMP];

    #pragma unroll
    for (int t = 0; t < 4; ++t) {
        #pragma unroll
        for (int k = 0; k < KCOMP; ++k) {
            f32x4 d4 = __builtin_amdgcn_mfma_f32_16x16x32_bf16(
                           afrag[k], bfrag[t], zero4, 0, 0, 0);
            float p = d4[0]*d4[0] + d4[1]*d4[1] + d4[2]*d4[2] + d4[3]*d4[3];
            p += __shfl_xor(p, 16, 64);
            p += __shfl_xor(p, 32, 64);          // all lanes: maha of sample col m, tile t
            float lpv = fmaf(-0.5f, p, ck[k]);
            if (t == 0) lp[k] = lpv;             // every lane's quad matches exactly one t
            else        lp[k] = (quad == t) ? lpv : lp[k];
        }
    }

    // 8-component log-sum-exp for this lane's sample (base + lane)
    float mx = lp[0];
    #pragma unroll
    for (int k = 1; k < KCOMP; ++k) mx = fmaxf(mx, lp[k]);
    float dens = 0.0f;
    #pragma unroll
    for (int k = 0; k < KCOMP; ++k) dens += __expf(lp[k] - mx);

    const int so = base + lane;
    if (so < n) out[so] = -(mx + __logf(dens));
}

extern "C" void kernel_launch(void* const* d_in, const int* in_sizes, int n_in,
                              void* d_out, int out_size, void* d_ws, size_t ws_size,
                              hipStream_t stream) {
    const float* mu    = (const float*)d_in[0];
    const float* sigma = (const float*)d_in[1];
    const float* z     = (const float*)d_in[2];
    const float* pi    = (const float*)d_in[3];
    float* ws  = (float*)d_ws;
    float* out = (float*)d_out;

    const int n = in_sizes[2] / DDIM;   // number of samples (524288)

    prep_kernel<<<1, 128, 0, stream>>>(mu, sigma, pi, ws);

    // 64 samples per wave, 4 waves per block -> 256 samples/block
    const int blocks = (n + 255) / 256;   // 2048
    energy_kernel<<<blocks, 256, 0, stream>>>(z, ws, out, n);
}